// Round 1
// baseline (1106.780 us; speedup 1.0000x reference)
//
#include <hip/hip_runtime.h>
#include <hip/hip_bf16.h>

// ConvLSTM cell, N=256, DIN=256, DH=512, W=8 spatial.
// Strategy: bf16 MFMA GEMM. conv = sum of 9 shifted GEMMs over padded NHWC input.
//   M = 16384 (n*64 + y*8 + x), Ncols = 2048 (gate*512 + ch), K = 9 taps x 768 ch.
// Workspace layout (needs ~192.5 MiB):
//   pre : f32 [16384][2048]          = 134,217,728 B  (offset 0)
//   P   : bf16 [256][10][10][768]    =  39,321,600 B  (offset 134,217,728)
//   Wb  : bf16 [9][2048][768]        =  28,311,552 B  (offset 173,539,328)

#define DEVINL __device__ __forceinline__

typedef __attribute__((ext_vector_type(8))) short short8;
typedef __attribute__((ext_vector_type(4))) float f32x4;

DEVINL unsigned short f2bf(float f) {
  union { float f; unsigned u; } x; x.f = f;
  unsigned r = x.u + 0x7fffu + ((x.u >> 16) & 1u);   // RNE
  return (unsigned short)(r >> 16);
}

DEVINL void async16(const void* g, void* l) {
  __builtin_amdgcn_global_load_lds((const __attribute__((address_space(1))) void*)g,
                                   (__attribute__((address_space(3))) void*)l,
                                   16, 0, 0);
}

// ---------------------------------------------------------------- pack P
// P[n][yp][xp][c]: c<256 -> input[n][c][ys][xs]; else h0 = hidden_state[n][0][c-256][ys][xs]
// reflect pad: padded idx 0 -> src 1; 9 -> src 6; else idx-1
__global__ void __launch_bounds__(256) pack_p(const float* __restrict__ input,
                                              const float* __restrict__ hs,
                                              unsigned short* __restrict__ P) {
  int idx = blockIdx.x * 256 + threadIdx.x;        // 19,660,800 total, exact
  int c = idx % 768;
  int rest = idx / 768;                            // n*100 + yp*10 + xp
  int xp = rest % 10;
  int rest2 = rest / 10;                           // n*10 + yp
  int yp = rest2 % 10;
  int n  = rest2 / 10;
  int ys = (yp == 0) ? 1 : ((yp == 9) ? 6 : yp - 1);
  int xs = (xp == 0) ? 1 : ((xp == 9) ? 6 : xp - 1);
  float v;
  if (c < 256) {
    v = input[(size_t)((n * 256 + c) * 8 + ys) * 8 + xs];
  } else {
    // hidden_state shape (256,2,512,8,8); h0 slab at (n*2+0)
    v = hs[(size_t)n * 65536 + (size_t)(c - 256) * 64 + ys * 8 + xs];
  }
  P[idx] = f2bf(v);
}

// ---------------------------------------------------------------- pack W
// Wb[s][co][c], s=ky*3+kx, co=gate*512+och, c<256 -> w_x[gate][och][c][ky][kx], else w_h[...][c-256][...]
__global__ void __launch_bounds__(256) pack_w(const float* __restrict__ wx0, const float* __restrict__ wx1,
                                              const float* __restrict__ wx2, const float* __restrict__ wx3,
                                              const float* __restrict__ wh0, const float* __restrict__ wh1,
                                              const float* __restrict__ wh2, const float* __restrict__ wh3,
                                              unsigned short* __restrict__ Wb) {
  int idx = blockIdx.x * 256 + threadIdx.x;        // 14,155,776 total, exact
  int c = idx % 768;
  int rest = idx / 768;                            // s*2048 + co
  int co = rest % 2048;
  int s  = rest / 2048;
  int ky = s / 3, kx = s - ky * 3;
  int gate = co >> 9, och = co & 511;
  float v;
  if (c < 256) {
    const float* w = (gate == 0) ? wx0 : (gate == 1) ? wx1 : (gate == 2) ? wx2 : wx3;
    v = w[(size_t)((och * 256 + c) * 3 + ky) * 3 + kx];
  } else {
    const float* w = (gate == 0) ? wh0 : (gate == 1) ? wh1 : (gate == 2) ? wh2 : wh3;
    v = w[(size_t)((och * 512 + (c - 256)) * 3 + ky) * 3 + kx];
  }
  Wb[idx] = f2bf(v);
}

// ---------------------------------------------------------------- GEMM
// pre[m][co] = sum_{s,c} P[n][y+ky][x+kx][c] * Wb[s][co][c]
// 128x128 tile, BK=32, 4 waves (2x2), each wave 64x64 via 4x4 16x16x32 MFMA frags.
__global__ void __launch_bounds__(256) gemm_pre(const unsigned short* __restrict__ P,
                                                const unsigned short* __restrict__ Wb,
                                                float* __restrict__ pre) {
  __shared__ __align__(16) unsigned short As[128 * 32];  // [row128][k32]
  __shared__ __align__(16) unsigned short Bs[128 * 32];  // [col128][k32]

  int bid = blockIdx.x;
  int nb = bid & 15;    // 16 col-blocks of 128
  int mb = bid >> 4;    // 128 row-blocks of 128
  int t = threadIdx.x;
  int l = t & 63;
  int w = t >> 6;
  int wr = w >> 1, wc = w & 1;

  // --- staging address precompute ---
  int kp = t & 3;                       // 8-bf16 (16B) sub-slot within a 32-wide K row
  // A: slot q*256+t -> row = q*64 + (t>>2); m = mb*128 + row
  int rA = t >> 2;
  int m0 = mb * 128 + rA;
  int m1 = m0 + 64;
  int pA0 = ((m0 >> 6) * 100 + ((m0 >> 3) & 7) * 10 + (m0 & 7)) * 768 + kp * 8;
  int pA1 = ((m1 >> 6) * 100 + ((m1 >> 3) & 7) * 10 + (m1 & 7)) * 768 + kp * 8;
  // B: slot q*256+t -> col = q*64 + (t>>2)
  int wB0 = (nb * 128 + rA) * 768 + kp * 8;
  int wB1 = (nb * 128 + 64 + rA) * 768 + kp * 8;
  // wave-uniform LDS bases (elements): slot_base*8
  int lds0 = (t & ~63) * 8;             // call q=0: slots [w*64, w*64+64)
  int lds1 = (256 + (t & ~63)) * 8;     // call q=1

  // --- fragment read offsets ---
  int lm = l & 15, lk = l >> 4;
  int aoff = (wr * 64 + lm) * 32 + lk * 8;   // + i*512
  int boff = (wc * 64 + lm) * 32 + lk * 8;   // + j*512

  f32x4 acc[4][4];
#pragma unroll
  for (int i = 0; i < 4; ++i)
#pragma unroll
    for (int j = 0; j < 4; ++j) acc[i][j] = (f32x4){0.f, 0.f, 0.f, 0.f};

  for (int s = 0; s < 9; ++s) {
    int ky = s / 3, kx = s - ky * 3;
    const unsigned short* Pa = P + (ky * 10 + kx) * 768;
    const unsigned short* Wa = Wb + (size_t)s * (2048 * 768);
#pragma unroll 1
    for (int c0 = 0; c0 < 768; c0 += 32) {
      __syncthreads();   // previous iter's ds_reads done before overwrite
      async16(Pa + pA0 + c0, &As[lds0]);
      async16(Pa + pA1 + c0, &As[lds1]);
      async16(Wa + wB0 + c0, &Bs[lds0]);
      async16(Wa + wB1 + c0, &Bs[lds1]);
      __syncthreads();   // compiler drains vmcnt(0) before this barrier

      short8 a[4], b[4];
#pragma unroll
      for (int i = 0; i < 4; ++i) a[i] = *(const short8*)(&As[aoff + i * 512]);
#pragma unroll
      for (int j = 0; j < 4; ++j) b[j] = *(const short8*)(&Bs[boff + j * 512]);
#pragma unroll
      for (int i = 0; i < 4; ++i)
#pragma unroll
        for (int j = 0; j < 4; ++j)
          acc[i][j] = __builtin_amdgcn_mfma_f32_16x16x32_bf16(a[i], b[j], acc[i][j], 0, 0, 0);
    }
  }

  // epilogue: C/D layout col=lane&15, row=(lane>>4)*4+reg  [m89/m91 verified]
  int r0 = mb * 128 + wr * 64 + lk * 4;
  int cb = nb * 128 + wc * 64 + lm;
#pragma unroll
  for (int i = 0; i < 4; ++i)
#pragma unroll
    for (int j = 0; j < 4; ++j)
#pragma unroll
      for (int r = 0; r < 4; ++r)
        pre[(size_t)(r0 + i * 16 + r) * 2048 + cb + j * 16] = acc[i][j][r];
}

// ---------------------------------------------------------------- pointwise LSTM
__global__ void __launch_bounds__(256) lstm_pointwise(const float* __restrict__ pre,
                                                      const float* __restrict__ hs,
                                                      const float* __restrict__ bi, const float* __restrict__ bf_,
                                                      const float* __restrict__ bg, const float* __restrict__ bo,
                                                      const float* __restrict__ wci, const float* __restrict__ wcf,
                                                      const float* __restrict__ wco,
                                                      float* __restrict__ out) {
  int tid = blockIdx.x * 256 + threadIdx.x;   // 8,388,608 total, exact
  int p  = tid & 63;
  int ch = (tid >> 6) & 511;
  int n  = tid >> 15;
  int m = n * 64 + p;
  size_t base = (size_t)m * 2048 + ch;
  float pi = pre[base]        + bi[ch];
  float pf = pre[base + 512]  + bf_[ch];
  float pg = pre[base + 1024] + bg[ch];
  float po = pre[base + 1536] + bo[ch];
  int sp = ch * 64 + p;
  float c0 = hs[(size_t)n * 65536 + 32768 + sp];   // cell slab (n*2+1)
  float ig = 1.f / (1.f + __expf(-(pi + c0 * wci[sp])));
  float fg = 1.f / (1.f + __expf(-(pf + c0 * wcf[sp])));
  float gg = tanhf(pg);
  float ct = fg * c0 + ig * gg;
  float og = 1.f / (1.f + __expf(-(po + ct * wco[sp])));
  float ht = og * tanhf(ct);
  out[(size_t)(n * 512 + ch) * 64 + p] = og;                       // output 0: o
  float* hso = out + 8388608;                                      // output 1: stack([h_t, c_t], axis=1)
  hso[(size_t)(n * 1024 + ch) * 64 + p] = ht;                      // (n,0,ch)
  hso[(size_t)(n * 1024 + 512 + ch) * 64 + p] = ct;                // (n,1,ch)
}

// ---------------------------------------------------------------- launch
extern "C" void kernel_launch(void* const* d_in, const int* in_sizes, int n_in,
                              void* d_out, int out_size, void* d_ws, size_t ws_size,
                              hipStream_t stream) {
  const float* input = (const float*)d_in[0];
  const float* hs    = (const float*)d_in[1];
  const float* wx0 = (const float*)d_in[2];
  const float* wx1 = (const float*)d_in[3];
  const float* wx2 = (const float*)d_in[4];
  const float* wx3 = (const float*)d_in[5];
  const float* wh0 = (const float*)d_in[6];
  const float* wh1 = (const float*)d_in[7];
  const float* wh2 = (const float*)d_in[8];
  const float* wh3 = (const float*)d_in[9];
  const float* bi  = (const float*)d_in[10];
  const float* bf_ = (const float*)d_in[11];
  const float* bg  = (const float*)d_in[12];
  const float* bo  = (const float*)d_in[13];
  const float* wci = (const float*)d_in[14];
  const float* wcf = (const float*)d_in[15];
  const float* wco = (const float*)d_in[16];
  float* out = (float*)d_out;

  float*          pre = (float*)d_ws;
  unsigned short* P   = (unsigned short*)((char*)d_ws + 134217728u);
  unsigned short* Wb  = (unsigned short*)((char*)d_ws + 134217728u + 39321600u);

  pack_p<<<76800, 256, 0, stream>>>(input, hs, P);
  pack_w<<<55296, 256, 0, stream>>>(wx0, wx1, wx2, wx3, wh0, wh1, wh2, wh3, Wb);
  gemm_pre<<<2048, 256, 0, stream>>>(P, Wb, pre);
  lstm_pointwise<<<32768, 256, 0, stream>>>(pre, hs, bi, bf_, bg, bo, wci, wcf, wco, out);
}

// Round 4
// 655.459 us; speedup vs baseline: 1.6886x; 1.6886x over previous
//
#include <hip/hip_runtime.h>
#include <hip/hip_bf16.h>

// ConvLSTM cell, N=256, DIN=256, DH=512, W=8.
// pre[m][co] = sum_k P[win(m)+tap(k)][c(k)] * Wb2[co][k],  M=16384, N=2048, K=6912.
// Workspace:
//   pre : f32 [16384][2048]          = 134,217,728 B (offset 0)
//   P   : bf16 [256][10][10][768]    =  39,321,600 B (offset 134,217,728)
//   Wb2 : bf16 [2048][6912]          =  28,311,552 B (offset 173,539,328)

#define DEVINL __device__ __forceinline__

typedef __attribute__((ext_vector_type(8))) short short8;
typedef __attribute__((ext_vector_type(4))) float f32x4;
typedef __attribute__((ext_vector_type(4))) float float4v;

DEVINL unsigned short f2bf(float f) {
  union { float f; unsigned u; } x; x.f = f;
  unsigned r = x.u + 0x7fffu + ((x.u >> 16) & 1u);   // RNE
  return (unsigned short)(r >> 16);
}

DEVINL void async16(const void* g, void* l) {
  __builtin_amdgcn_global_load_lds((const __attribute__((address_space(1))) void*)g,
                                   (__attribute__((address_space(3))) void*)l,
                                   16, 0, 0);
}

// ---------------------------------------------------------------- pack P
// thread = (n, c): lanes c-fast. Reads 64 floats vectorized, writes 100 padded
// positions; each store coalesces to 128B across the wave.
__global__ void __launch_bounds__(256) pack_p(const float* __restrict__ input,
                                              const float* __restrict__ hs,
                                              unsigned short* __restrict__ P) {
  int idx = blockIdx.x * 256 + threadIdx.x;    // 196,608 = 256 n * 768 c
  int c = idx % 768;
  int n = idx / 768;
  const float* src;
  if (c < 256) src = input + (size_t)(n * 256 + c) * 64;
  else         src = hs + (size_t)n * 65536 + (size_t)(c - 256) * 64;

  float v[64];
#pragma unroll
  for (int i = 0; i < 16; ++i) {
    float4v q = *(const float4v*)(src + i * 4);
    v[i * 4 + 0] = q.x; v[i * 4 + 1] = q.y; v[i * 4 + 2] = q.z; v[i * 4 + 3] = q.w;
  }
  unsigned short bv[64];
#pragma unroll
  for (int i = 0; i < 64; ++i) bv[i] = f2bf(v[i]);

  size_t base = (size_t)n * 76800 + c;   // n*100*768 + c
#pragma unroll
  for (int yp = 0; yp < 10; ++yp) {
    const int ys = (yp == 0) ? 1 : ((yp == 9) ? 6 : yp - 1);
#pragma unroll
    for (int xp = 0; xp < 10; ++xp) {
      const int xs = (xp == 0) ? 1 : ((xp == 9) ? 6 : xp - 1);
      P[base + (yp * 10 + xp) * 768] = bv[ys * 8 + xs];
    }
  }
}

// ---------------------------------------------------------------- pack W
// Wb2[co][k], k = ky*2304 + kx*768 + c. thread = (co, c), lanes c-fast:
// reads its 9 taps contiguously (36B), writes coalesced per tap.
__global__ void __launch_bounds__(256) pack_w(const float* __restrict__ wx0, const float* __restrict__ wx1,
                                              const float* __restrict__ wx2, const float* __restrict__ wx3,
                                              const float* __restrict__ wh0, const float* __restrict__ wh1,
                                              const float* __restrict__ wh2, const float* __restrict__ wh3,
                                              unsigned short* __restrict__ Wb) {
  int idx = blockIdx.x * 256 + threadIdx.x;    // 1,572,864 = 2048 co * 768 c
  int c = idx % 768;
  int co = idx / 768;
  int gate = co >> 9, och = co & 511;
  const float* w;
  size_t wbase;
  if (c < 256) {
    w = (gate == 0) ? wx0 : (gate == 1) ? wx1 : (gate == 2) ? wx2 : wx3;
    wbase = (size_t)(och * 256 + c) * 9;
  } else {
    w = (gate == 0) ? wh0 : (gate == 1) ? wh1 : (gate == 2) ? wh2 : wh3;
    wbase = (size_t)(och * 512 + (c - 256)) * 9;
  }
  float v[9];
#pragma unroll
  for (int s = 0; s < 9; ++s) v[s] = w[wbase + s];
  size_t ob = (size_t)co * 6912 + c;
#pragma unroll
  for (int ky = 0; ky < 3; ++ky)
#pragma unroll
    for (int kx = 0; kx < 3; ++kx)
      Wb[ob + ky * 2304 + kx * 768] = f2bf(v[ky * 3 + kx]);
}

// ---------------------------------------------------------------- GEMM (256x256, 8-phase)
// 512 thr = 8 waves (2 M x 4 N). BK=64 (2 k-halves of 32). LDS 128 KiB:
//   A: lds[d*16384 + ks*8192 + row*32 + swz]   d=dbuf, row 0..255
//   B: lds[32768 + d*16384 + ks*8192 + col*32 + swz]
// swizzle: 16B slot ^= (row>>1)&3, applied as inverse-swizzled GLOBAL source +
// swizzled read (rule 21: gload_lds dest stays linear).
#define NT 108

__global__ void __launch_bounds__(512, 2) gemm_pre(const unsigned short* __restrict__ P,
                                                   const unsigned short* __restrict__ W,
                                                   float* __restrict__ pre) {
  __shared__ __align__(16) unsigned short lds[65536];

  const int t = threadIdx.x;
  const int l = t & 63;
  const int wid = t >> 6;
  const int wr = wid >> 2, wc = wid & 3;
  const int lm = l & 15, lk = l >> 4;

  int bid = blockIdx.x;                 // 512 wgs, 8 XCDs
  const int x8 = bid & 7, j = bid >> 3;
  const int mb = x8 * 8 + (j & 7);      // 64 row-blocks of 256
  const int nb = j >> 3;                // 8 col-blocks of 256

  // ---- staging coords (per thread): row = q*128 + (t>>2), k-slot inverse-swizzled
  const int strow = t >> 2;                              // [0,128)
  const int stk = (((t & 3) ^ ((t >> 3) & 3)) << 3);     // [0,32) mult of 8
  const int am0 = mb * 256 + strow;
  const int am1 = am0 + 128;
  const int awin0 = ((am0 >> 6) * 100 + ((am0 >> 3) & 7) * 10 + (am0 & 7)) * 768 + stk;
  const int awin1 = ((am1 >> 6) * 100 + ((am1 >> 3) & 7) * 10 + (am1 & 7)) * 768 + stk;
  const size_t bb0 = (size_t)(nb * 256 + strow) * 6912 + stk;
  const size_t bb1 = bb0 + (size_t)128 * 6912;
  const int dstT = t * 8;                                // linear LDS dest (elems)

  // ---- fragment read offsets (elems), swizzled
  const int swz = ((lk ^ ((lm >> 1) & 3)) << 3);
  const int aoffb = (wr * 128 + lm) * 32 + swz;
  const int boffb = 32768 + (wc * 64 + lm) * 32 + swz;   // includes B-region base

#define STAGE_A(TS, KS, D) { \
    int kg = (TS) * 64 + (KS) * 32; \
    int ky = kg / 2304; \
    int off = kg + ky * 5376; \
    async16(P + awin0 + off, &lds[(D) * 16384 + (KS) * 8192 + dstT]); \
    async16(P + awin1 + off, &lds[(D) * 16384 + (KS) * 8192 + 4096 + dstT]); }

#define STAGE_B(TS, KS, D) { \
    int kg = (TS) * 64 + (KS) * 32; \
    async16(W + bb0 + kg, &lds[32768 + (D) * 16384 + (KS) * 8192 + dstT]); \
    async16(W + bb1 + kg, &lds[32768 + (D) * 16384 + (KS) * 8192 + 4096 + dstT]); }

#define DS_A(D, KS, M) (*(const short8*)&lds[(D) * 16384 + (KS) * 8192 + (M) * 512 + aoffb])
// NOTE: base 32768 lives in boffb ONLY (round-3 bug: it was added here too -> OOB reads)
#define DS_B(D, KS, Nn) (*(const short8*)&lds[(D) * 16384 + (KS) * 8192 + (Nn) * 512 + boffb])

#define LGKM0 asm volatile("s_waitcnt lgkmcnt(0)" ::: "memory")
#define VMC8  asm volatile("s_waitcnt vmcnt(8)" ::: "memory")

  f32x4 acc[8][4];
#pragma unroll
  for (int i = 0; i < 8; ++i)
#pragma unroll
    for (int n2 = 0; n2 < 4; ++n2) acc[i][n2] = (f32x4){0.f, 0.f, 0.f, 0.f};

  short8 a[4], b[4];

  // ---- prologue: K0 full + K1 kh0 (12 loads); vmcnt(8) -> oldest 4 (K0 kh0) done
  STAGE_A(0, 0, 0); STAGE_B(0, 0, 0);
  STAGE_A(0, 1, 0); STAGE_B(0, 1, 0);
  STAGE_A(1, 0, 1); STAGE_B(1, 0, 1);
  VMC8;
  __builtin_amdgcn_s_barrier();

#define MFMA_BLK(MB) \
  _Pragma("unroll") for (int mm = 0; mm < 4; ++mm) \
  _Pragma("unroll") for (int nn = 0; nn < 4; ++nn) \
    acc[(MB) + mm][nn] = __builtin_amdgcn_mfma_f32_16x16x32_bf16(a[mm], b[nn], acc[(MB) + mm][nn], 0, 0, 0);

#pragma unroll 2
  for (int tau = 0; tau < NT; ++tau) {
    const int d = tau & 1;
    int t1 = tau + 1; if (t1 >= NT) t1 -= NT;
    int t2 = tau + 2; if (t2 >= NT) t2 -= NT;

    // phase 0: compute ks0, m0-3 ; stage A-ks1(tau+1)
#pragma unroll
    for (int mm = 0; mm < 4; ++mm) a[mm] = DS_A(d, 0, mm);
#pragma unroll
    for (int nn = 0; nn < 4; ++nn) b[nn] = DS_B(d, 0, nn);
    STAGE_A(t1, 1, d ^ 1);
    __builtin_amdgcn_s_barrier();
    LGKM0;
    __builtin_amdgcn_s_setprio(1);
    MFMA_BLK(0);
    __builtin_amdgcn_s_setprio(0);
    __builtin_amdgcn_s_barrier();

    // phase 1: compute ks0, m4-7 ; stage B-ks1(tau+1)
#pragma unroll
    for (int mm = 0; mm < 4; ++mm) a[mm] = DS_A(d, 0, 4 + mm);
    STAGE_B(t1, 1, d ^ 1);
    __builtin_amdgcn_s_barrier();
    LGKM0;
    __builtin_amdgcn_s_setprio(1);
    MFMA_BLK(4);
    __builtin_amdgcn_s_setprio(0);
    VMC8;
    __builtin_amdgcn_s_barrier();

    // phase 2: compute ks1, m0-3 ; stage A-ks0(tau+2)
#pragma unroll
    for (int mm = 0; mm < 4; ++mm) a[mm] = DS_A(d, 1, mm);
#pragma unroll
    for (int nn = 0; nn < 4; ++nn) b[nn] = DS_B(d, 1, nn);
    STAGE_A(t2, 0, d);
    __builtin_amdgcn_s_barrier();
    LGKM0;
    __builtin_amdgcn_s_setprio(1);
    MFMA_BLK(0);
    __builtin_amdgcn_s_setprio(0);
    __builtin_amdgcn_s_barrier();

    // phase 3: compute ks1, m4-7 ; stage B-ks0(tau+2)
#pragma unroll
    for (int mm = 0; mm < 4; ++mm) a[mm] = DS_A(d, 1, 4 + mm);
    STAGE_B(t2, 0, d);
    __builtin_amdgcn_s_barrier();
    LGKM0;
    __builtin_amdgcn_s_setprio(1);
    MFMA_BLK(4);
    __builtin_amdgcn_s_setprio(0);
    VMC8;
    __builtin_amdgcn_s_barrier();
  }

  // ---- epilogue: C/D layout col=lane&15, row=(lane>>4)*4+reg
  const int r0 = mb * 256 + wr * 128 + lk * 4;
  const int cb = nb * 256 + wc * 64 + lm;
#pragma unroll
  for (int mm = 0; mm < 8; ++mm)
#pragma unroll
    for (int nn = 0; nn < 4; ++nn)
#pragma unroll
      for (int r = 0; r < 4; ++r)
        pre[(size_t)(r0 + mm * 16 + r) * 2048 + cb + nn * 16] = acc[mm][nn][r];
}

// ---------------------------------------------------------------- pointwise LSTM
// block = (n, chb): 64ch x 64p tile. Load pre ch-fast coalesced -> LDS,
// compute/write p-fast coalesced. [4][64][65] f32 = 66,560 B LDS.
__global__ void __launch_bounds__(256) lstm_pointwise(const float* __restrict__ pre,
                                                      const float* __restrict__ hs,
                                                      const float* __restrict__ bi, const float* __restrict__ bf_,
                                                      const float* __restrict__ bg, const float* __restrict__ bo,
                                                      const float* __restrict__ wci, const float* __restrict__ wcf,
                                                      const float* __restrict__ wco,
                                                      float* __restrict__ out) {
  __shared__ float g[4][64][65];
  const int blk = blockIdx.x;           // 2048 = 256 n * 8 chb
  const int n = blk >> 3, chb = blk & 7;
  const int t = threadIdx.x;

  {
    const int chl = t & 63, pr = t >> 6;
#pragma unroll
    for (int it = 0; it < 16; ++it) {
      int p = it * 4 + pr;
      size_t rowb = (size_t)(n * 64 + p) * 2048 + chb * 64 + chl;
      g[0][p][chl] = pre[rowb];
      g[1][p][chl] = pre[rowb + 512];
      g[2][p][chl] = pre[rowb + 1024];
      g[3][p][chl] = pre[rowb + 1536];
    }
  }
  __syncthreads();
  {
    const int pl = t & 63, chr = t >> 6;
#pragma unroll 4
    for (int it = 0; it < 16; ++it) {
      int chi = it * 4 + chr;
      int ch = chb * 64 + chi;
      int sp = ch * 64 + pl;
      float c0 = hs[(size_t)n * 65536 + 32768 + sp];
      float pi = g[0][pl][chi] + bi[ch];
      float pf = g[1][pl][chi] + bf_[ch];
      float pg = g[2][pl][chi] + bg[ch];
      float po = g[3][pl][chi] + bo[ch];
      float ig = 1.f / (1.f + __expf(-(pi + c0 * wci[sp])));
      float fg = 1.f / (1.f + __expf(-(pf + c0 * wcf[sp])));
      float gg = tanhf(pg);
      float ct = fg * c0 + ig * gg;
      float og = 1.f / (1.f + __expf(-(po + ct * wco[sp])));
      float ht = og * tanhf(ct);
      out[(size_t)(n * 512 + ch) * 64 + pl] = og;
      float* hso = out + 8388608;
      hso[(size_t)(n * 1024 + ch) * 64 + pl] = ht;
      hso[(size_t)(n * 1024 + 512 + ch) * 64 + pl] = ct;
    }
  }
}

// ---------------------------------------------------------------- launch
extern "C" void kernel_launch(void* const* d_in, const int* in_sizes, int n_in,
                              void* d_out, int out_size, void* d_ws, size_t ws_size,
                              hipStream_t stream) {
  const float* input = (const float*)d_in[0];
  const float* hs    = (const float*)d_in[1];
  const float* wx0 = (const float*)d_in[2];
  const float* wx1 = (const float*)d_in[3];
  const float* wx2 = (const float*)d_in[4];
  const float* wx3 = (const float*)d_in[5];
  const float* wh0 = (const float*)d_in[6];
  const float* wh1 = (const float*)d_in[7];
  const float* wh2 = (const float*)d_in[8];
  const float* wh3 = (const float*)d_in[9];
  const float* bi  = (const float*)d_in[10];
  const float* bf_ = (const float*)d_in[11];
  const float* bg  = (const float*)d_in[12];
  const float* bo  = (const float*)d_in[13];
  const float* wci = (const float*)d_in[14];
  const float* wcf = (const float*)d_in[15];
  const float* wco = (const float*)d_in[16];
  float* out = (float*)d_out;

  float*          pre = (float*)d_ws;
  unsigned short* P   = (unsigned short*)((char*)d_ws + 134217728u);
  unsigned short* Wb  = (unsigned short*)((char*)d_ws + 134217728u + 39321600u);

  pack_p<<<768, 256, 0, stream>>>(input, hs, P);
  pack_w<<<6144, 256, 0, stream>>>(wx0, wx1, wx2, wx3, wh0, wh1, wh2, wh3, Wb);
  gemm_pre<<<512, 512, 0, stream>>>(P, Wb, pre);
  lstm_pointwise<<<2048, 256, 0, stream>>>(pre, hs, bi, bf_, bg, bo, wci, wcf, wco, out);
}

// Round 5
// 641.045 us; speedup vs baseline: 1.7265x; 1.0225x over previous
//
#include <hip/hip_runtime.h>
#include <hip/hip_bf16.h>

// ConvLSTM cell, N=256, DIN=256, DH=512, W=8.
// Fused: conv-GEMM (M=16384, Ncol=2048, K=6912) + LSTM pointwise epilogue.
// B-column permutation: GEMM col c = q*64 + gate*16 + lm  <->  gate, ch=q*16+lm,
// so each lane's 4 nn-fragments are the 4 gates of one (m, ch) element.
// Workspace:
//   P   : bf16 [256][10][10][768]    = 39,321,600 B (offset 0)
//   Wb2 : bf16 [2048][6912]          = 28,311,552 B (offset 39,321,600)

#define DEVINL __device__ __forceinline__

typedef __attribute__((ext_vector_type(8))) short short8;
typedef __attribute__((ext_vector_type(4))) float f32x4;
typedef __attribute__((ext_vector_type(4))) float float4v;

DEVINL unsigned short f2bf(float f) {
  union { float f; unsigned u; } x; x.f = f;
  unsigned r = x.u + 0x7fffu + ((x.u >> 16) & 1u);   // RNE
  return (unsigned short)(r >> 16);
}

DEVINL float sigm(float x) { return 1.f / (1.f + __expf(-x)); }
DEVINL float tanh_fast(float x) { return 1.f - 2.f / (1.f + __expf(2.f * x)); }

DEVINL void async16(const void* g, void* l) {
  __builtin_amdgcn_global_load_lds((const __attribute__((address_space(1))) void*)g,
                                   (__attribute__((address_space(3))) void*)l,
                                   16, 0, 0);
}

// ---------------------------------------------------------------- pack P
__global__ void __launch_bounds__(256) pack_p(const float* __restrict__ input,
                                              const float* __restrict__ hs,
                                              unsigned short* __restrict__ P) {
  int idx = blockIdx.x * 256 + threadIdx.x;    // 196,608 = 256 n * 768 c
  int c = idx % 768;
  int n = idx / 768;
  const float* src;
  if (c < 256) src = input + (size_t)(n * 256 + c) * 64;
  else         src = hs + (size_t)n * 65536 + (size_t)(c - 256) * 64;

  float v[64];
#pragma unroll
  for (int i = 0; i < 16; ++i) {
    float4v q = *(const float4v*)(src + i * 4);
    v[i * 4 + 0] = q.x; v[i * 4 + 1] = q.y; v[i * 4 + 2] = q.z; v[i * 4 + 3] = q.w;
  }
  unsigned short bv[64];
#pragma unroll
  for (int i = 0; i < 64; ++i) bv[i] = f2bf(v[i]);

  size_t base = (size_t)n * 76800 + c;   // n*100*768 + c
#pragma unroll
  for (int yp = 0; yp < 10; ++yp) {
    const int ys = (yp == 0) ? 1 : ((yp == 9) ? 6 : yp - 1);
#pragma unroll
    for (int xp = 0; xp < 10; ++xp) {
      const int xs = (xp == 0) ? 1 : ((xp == 9) ? 6 : xp - 1);
      P[base + (yp * 10 + xp) * 768] = bv[ys * 8 + xs];
    }
  }
}

// ---------------------------------------------------------------- pack W
// GEMM-row (B-row) for logical (gate, ch): crow = (ch>>4)*64 + gate*16 + (ch&15).
// k = ky*2304 + kx*768 + c.
__global__ void __launch_bounds__(256) pack_w(const float* __restrict__ wx0, const float* __restrict__ wx1,
                                              const float* __restrict__ wx2, const float* __restrict__ wx3,
                                              const float* __restrict__ wh0, const float* __restrict__ wh1,
                                              const float* __restrict__ wh2, const float* __restrict__ wh3,
                                              unsigned short* __restrict__ Wb) {
  int idx = blockIdx.x * 256 + threadIdx.x;    // 1,572,864 = 2048 co * 768 c
  int c = idx % 768;
  int co = idx / 768;
  int gate = co >> 9, och = co & 511;
  const float* w;
  size_t wbase;
  if (c < 256) {
    w = (gate == 0) ? wx0 : (gate == 1) ? wx1 : (gate == 2) ? wx2 : wx3;
    wbase = (size_t)(och * 256 + c) * 9;
  } else {
    w = (gate == 0) ? wh0 : (gate == 1) ? wh1 : (gate == 2) ? wh2 : wh3;
    wbase = (size_t)(och * 512 + (c - 256)) * 9;
  }
  float v[9];
#pragma unroll
  for (int s = 0; s < 9; ++s) v[s] = w[wbase + s];
  const int crow = (och >> 4) * 64 + gate * 16 + (och & 15);
  size_t ob = (size_t)crow * 6912 + c;
#pragma unroll
  for (int ky = 0; ky < 3; ++ky)
#pragma unroll
    for (int kx = 0; kx < 3; ++kx)
      Wb[ob + ky * 2304 + kx * 768] = f2bf(v[ky * 3 + kx]);
}

// ---------------------------------------------------------------- fused GEMM + LSTM
// 512 thr = 8 waves (2 M x 4 N). BK=64 (2 k-halves of 32). LDS 128 KiB.
// swizzle: 16B slot ^= (row>>1)&3 (inverse-swizzled global source, swizzled read).
#define NT 108

__global__ void __launch_bounds__(512, 2) gemm_lstm(const unsigned short* __restrict__ P,
                                                    const unsigned short* __restrict__ W,
                                                    const float* __restrict__ hs,
                                                    const float* __restrict__ b_i, const float* __restrict__ b_f,
                                                    const float* __restrict__ b_g, const float* __restrict__ b_o,
                                                    const float* __restrict__ wci, const float* __restrict__ wcf,
                                                    const float* __restrict__ wco,
                                                    float* __restrict__ out) {
  __shared__ __align__(16) unsigned short lds[65536];

  const int t = threadIdx.x;
  const int l = t & 63;
  const int wid = t >> 6;
  const int wr = wid >> 2, wc = wid & 3;
  const int lm = l & 15, lk = l >> 4;

  int bid = blockIdx.x;                 // 512 wgs, 8 XCDs
  const int x8 = bid & 7, j = bid >> 3;
  const int mb = x8 * 8 + (j & 7);      // 64 row-blocks of 256
  const int nb = j >> 3;                // 8 col-blocks of 256

  // ---- staging coords: row = q*128 + (t>>2), k-slot inverse-swizzled
  const int strow = t >> 2;                              // [0,128)
  const int stk = (((t & 3) ^ ((t >> 3) & 3)) << 3);     // [0,32) mult of 8
  const int am0 = mb * 256 + strow;
  const int am1 = am0 + 128;
  const int awin0 = ((am0 >> 6) * 100 + ((am0 >> 3) & 7) * 10 + (am0 & 7)) * 768 + stk;
  const int awin1 = ((am1 >> 6) * 100 + ((am1 >> 3) & 7) * 10 + (am1 & 7)) * 768 + stk;
  const size_t bb0 = (size_t)(nb * 256 + strow) * 6912 + stk;
  const size_t bb1 = bb0 + (size_t)128 * 6912;
  const int dstT = t * 8;                                // linear LDS dest (elems)

  // ---- fragment read offsets (elems), swizzled
  const int swz = ((lk ^ ((lm >> 1) & 3)) << 3);
  const int aoffb = (wr * 128 + lm) * 32 + swz;
  const int boffb = 32768 + (wc * 64 + lm) * 32 + swz;   // includes B-region base

#define STAGE_A(TS, KS, D) { \
    int kg = (TS) * 64 + (KS) * 32; \
    int ky = kg / 2304; \
    int off = kg + ky * 5376; \
    async16(P + awin0 + off, &lds[(D) * 16384 + (KS) * 8192 + dstT]); \
    async16(P + awin1 + off, &lds[(D) * 16384 + (KS) * 8192 + 4096 + dstT]); }

#define STAGE_B(TS, KS, D) { \
    int kg = (TS) * 64 + (KS) * 32; \
    async16(W + bb0 + kg, &lds[32768 + (D) * 16384 + (KS) * 8192 + dstT]); \
    async16(W + bb1 + kg, &lds[32768 + (D) * 16384 + (KS) * 8192 + 4096 + dstT]); }

#define DS_A(D, KS, M) (*(const short8*)&lds[(D) * 16384 + (KS) * 8192 + (M) * 512 + aoffb])
#define DS_B(D, KS, Nn) (*(const short8*)&lds[(D) * 16384 + (KS) * 8192 + (Nn) * 512 + boffb])

#define LGKM0 asm volatile("s_waitcnt lgkmcnt(0)" ::: "memory")
#define VMC8  asm volatile("s_waitcnt vmcnt(8)" ::: "memory")

  f32x4 acc[8][4];
#pragma unroll
  for (int i = 0; i < 8; ++i)
#pragma unroll
    for (int n2 = 0; n2 < 4; ++n2) acc[i][n2] = (f32x4){0.f, 0.f, 0.f, 0.f};

  short8 a[4], b[4];

  // ---- prologue: K0 full + K1 kh0 (12 loads); vmcnt(8) -> oldest 4 done
  STAGE_A(0, 0, 0); STAGE_B(0, 0, 0);
  STAGE_A(0, 1, 0); STAGE_B(0, 1, 0);
  STAGE_A(1, 0, 1); STAGE_B(1, 0, 1);
  VMC8;
  __builtin_amdgcn_s_barrier();

#define MFMA_BLK(MB) \
  _Pragma("unroll") for (int mm = 0; mm < 4; ++mm) \
  _Pragma("unroll") for (int nn = 0; nn < 4; ++nn) \
    acc[(MB) + mm][nn] = __builtin_amdgcn_mfma_f32_16x16x32_bf16(a[mm], b[nn], acc[(MB) + mm][nn], 0, 0, 0);

#pragma unroll 2
  for (int tau = 0; tau < NT; ++tau) {
    const int d = tau & 1;
    int t1 = tau + 1; if (t1 >= NT) t1 -= NT;
    int t2 = tau + 2; if (t2 >= NT) t2 -= NT;

    // phase 0: compute ks0, m0-3 ; stage A-ks1(tau+1)
#pragma unroll
    for (int mm = 0; mm < 4; ++mm) a[mm] = DS_A(d, 0, mm);
#pragma unroll
    for (int nn = 0; nn < 4; ++nn) b[nn] = DS_B(d, 0, nn);
    STAGE_A(t1, 1, d ^ 1);
    __builtin_amdgcn_s_barrier();
    LGKM0;
    __builtin_amdgcn_s_setprio(1);
    MFMA_BLK(0);
    __builtin_amdgcn_s_setprio(0);
    __builtin_amdgcn_s_barrier();

    // phase 1: compute ks0, m4-7 ; stage B-ks1(tau+1)
#pragma unroll
    for (int mm = 0; mm < 4; ++mm) a[mm] = DS_A(d, 0, 4 + mm);
    STAGE_B(t1, 1, d ^ 1);
    __builtin_amdgcn_s_barrier();
    LGKM0;
    __builtin_amdgcn_s_setprio(1);
    MFMA_BLK(4);
    __builtin_amdgcn_s_setprio(0);
    VMC8;
    __builtin_amdgcn_s_barrier();

    // phase 2: compute ks1, m0-3 ; stage A-ks0(tau+2)
#pragma unroll
    for (int mm = 0; mm < 4; ++mm) a[mm] = DS_A(d, 1, mm);
#pragma unroll
    for (int nn = 0; nn < 4; ++nn) b[nn] = DS_B(d, 1, nn);
    STAGE_A(t2, 0, d);
    __builtin_amdgcn_s_barrier();
    LGKM0;
    __builtin_amdgcn_s_setprio(1);
    MFMA_BLK(0);
    __builtin_amdgcn_s_setprio(0);
    __builtin_amdgcn_s_barrier();

    // phase 3: compute ks1, m4-7 ; stage B-ks0(tau+2)
#pragma unroll
    for (int mm = 0; mm < 4; ++mm) a[mm] = DS_A(d, 1, 4 + mm);
    STAGE_B(t2, 0, d);
    __builtin_amdgcn_s_barrier();
    LGKM0;
    __builtin_amdgcn_s_setprio(1);
    MFMA_BLK(4);
    __builtin_amdgcn_s_setprio(0);
    VMC8;
    __builtin_amdgcn_s_barrier();
  }

  // ---- fused LSTM epilogue -----------------------------------------------
  // C/D layout: col=lane&15, row=(lane>>4)*4+reg. GEMM col c = q*64+gate*16+lm,
  // q = nb*4+wc  =>  ch = q*16+lm; acc[mm][gate][r] are the 4 gate pre-acts.
  const int ch = (nb * 4 + wc) * 16 + lm;
  const int chp = ch * 64;
  const float bI = b_i[ch], bF = b_f[ch], bG = b_g[ch], bO = b_o[ch];
  float* hso = out + 8388608;
#pragma unroll
  for (int mm = 0; mm < 8; ++mm) {
    const int n = mb * 4 + wr * 2 + (mm >> 2);
    const float* c0p = hs + (size_t)n * 65536 + 32768 + chp;   // cell slab (n,1,ch,:)
#pragma unroll
    for (int r = 0; r < 4; ++r) {
      const int p = (mm & 3) * 16 + lk * 4 + r;
      const float c0 = c0p[p];
      const float pi = acc[mm][0][r] + bI;
      const float pf = acc[mm][1][r] + bF;
      const float pg = acc[mm][2][r] + bG;
      const float po = acc[mm][3][r] + bO;
      const float ig = sigm(pi + c0 * wci[chp + p]);
      const float fg = sigm(pf + c0 * wcf[chp + p]);
      const float gg = tanh_fast(pg);
      const float ct = fg * c0 + ig * gg;
      const float og = sigm(po + ct * wco[chp + p]);
      const float ht = og * tanh_fast(ct);
      out[(size_t)n * 32768 + chp + p] = og;                   // o
      hso[(size_t)n * 65536 + chp + p] = ht;                   // (n,0,ch,p)
      hso[(size_t)n * 65536 + 32768 + chp + p] = ct;           // (n,1,ch,p)
    }
  }
}

// ---------------------------------------------------------------- launch
extern "C" void kernel_launch(void* const* d_in, const int* in_sizes, int n_in,
                              void* d_out, int out_size, void* d_ws, size_t ws_size,
                              hipStream_t stream) {
  const float* input = (const float*)d_in[0];
  const float* hs    = (const float*)d_in[1];
  const float* wx0 = (const float*)d_in[2];
  const float* wx1 = (const float*)d_in[3];
  const float* wx2 = (const float*)d_in[4];
  const float* wx3 = (const float*)d_in[5];
  const float* wh0 = (const float*)d_in[6];
  const float* wh1 = (const float*)d_in[7];
  const float* wh2 = (const float*)d_in[8];
  const float* wh3 = (const float*)d_in[9];
  const float* bi  = (const float*)d_in[10];
  const float* bf_ = (const float*)d_in[11];
  const float* bg  = (const float*)d_in[12];
  const float* bo  = (const float*)d_in[13];
  const float* wci = (const float*)d_in[14];
  const float* wcf = (const float*)d_in[15];
  const float* wco = (const float*)d_in[16];
  float* out = (float*)d_out;

  unsigned short* P  = (unsigned short*)d_ws;
  unsigned short* Wb = (unsigned short*)((char*)d_ws + 39321600u);

  pack_p<<<768, 256, 0, stream>>>(input, hs, P);
  pack_w<<<6144, 256, 0, stream>>>(wx0, wx1, wx2, wx3, wh0, wh1, wh2, wh3, Wb);
  gemm_lstm<<<512, 512, 0, stream>>>(P, Wb, hs, bi, bf_, bg, bo, wci, wcf, wco, out);
}